// Round 9
// baseline (512.360 us; speedup 1.0000x reference)
//
#include <hip/hip_runtime.h>
#include <hip/hip_bf16.h>

typedef unsigned short u16;
typedef u16 u16x8 __attribute__((ext_vector_type(8)));
typedef short s16x8 __attribute__((ext_vector_type(8)));
typedef float f32x4 __attribute__((ext_vector_type(4)));
typedef unsigned int u32;

#define NN 24
#define TT 49
#define MR 784                  // B*T = 16*49
#define SZT 4816896             // B*T*N*H

__device__ inline u16 f2b(float f){
    __hip_bfloat16 b = __float2bfloat16(f); u16 r; __builtin_memcpy(&r, &b, 2); return r;
}
__device__ inline float sig_(float x){ return 1.f / (1.f + __expf(-x)); }
__device__ inline float tanh_(float x){ float e = __expf(2.f * x); return (e - 1.f) / (e + 1.f); }

// global->LDS DMA, 16B per lane (global_load_lds_dwordx4)
__device__ inline void gld16(const u16* g, u16* l){
    __builtin_amdgcn_global_load_lds(
        (const __attribute__((address_space(1))) unsigned int*)g,
        (__attribute__((address_space(3))) unsigned int*)l, 16, 0, 0);
}

// ws layout: WT0 bf16 [216][56][256][32] | WT1 bf16 [144][16][256][32] | Abf bf16 [24][56][784][32]
#define WT0_ELEMS ((size_t)216 * 256 * 1792)
#define WT1_ELEMS ((size_t)144 * 256 * 512)
#define ABF_ELEMS ((size_t)24 * 56 * 784 * 32)
#define NEED_BASE ((WT0_ELEMS + WT1_ELEMS) * 2)
#define NEED_A    (NEED_BASE + ABF_ELEMS * 2 + 4096)

// ===========================================================================
// Prepass: weight f32 [k][col] -> bf16 k-tiled [kt][col][32], concat per slab.
// ===========================================================================
__global__ __launch_bounds__(256) void wprep0(
    const float* __restrict__ U,  const float* __restrict__ Wt,
    const float* __restrict__ Ws, const float* __restrict__ Zt,
    const float* __restrict__ Zs, u16* __restrict__ out)
{
    __shared__ u16 T[64][72];
    const int tid = threadIdx.x;
    const int kt = blockIdx.x, ct = blockIdx.y, z = blockIdx.z;
    const int n = z % NN, g = z / NN;
    const int k0 = kt * 64;

    const float* wbase;           // row k0 of the segment, 256-col rows
    if (k0 < 256)       wbase = U  + (size_t)((g * NN + n) * 256 + k0)          * 256;
    else if (k0 < 1024) wbase = Wt + (size_t)((g * NN + n) * 768 + (k0 - 256))  * 256;
    else if (k0 < 1280) wbase = Ws + (size_t)((g * NN + n) * 256 + (k0 - 1024)) * 256;
    else if (k0 < 1536) wbase = Zt + (size_t)((g * NN + n) * 256 + (k0 - 1280)) * 256;
    else { const int g2 = (g == 2) ? 1 : g;      // Zs_eff: f_ft uses Zs[lt]
           wbase = Zs + (size_t)((g2 * NN + n) * 256 + (k0 - 1536)) * 256; }

    const int colg = ct * 64 + (tid & 15) * 4;
    #pragma unroll
    for (int it = 0; it < 4; ++it) {
        const int krl = (tid >> 4) + it * 16;
        const float4 v = *(const float4*)(wbase + (size_t)krl * 256 + colg);
        const int cl = (tid & 15) * 4;
        T[cl + 0][krl] = f2b(v.x); T[cl + 1][krl] = f2b(v.y);
        T[cl + 2][krl] = f2b(v.z); T[cl + 3][krl] = f2b(v.w);
    }
    __syncthreads();
    const int col_l = tid >> 2, ks = (tid & 3) * 16;
    const int ktile = 2 * kt + (ks >> 5);          // global 32-k tile
    const int koff  = ks & 31;
    u16* dst = out + (size_t)z * 458752 + (size_t)ktile * 8192
                   + (size_t)(ct * 64 + col_l) * 32 + koff;
    u16x8 w0, w1;
    #pragma unroll
    for (int j = 0; j < 8; ++j) { w0[j] = T[col_l][ks + j]; w1[j] = T[col_l][ks + 8 + j]; }
    *(u16x8*)(dst) = w0; *(u16x8*)(dst + 8) = w1;
}

__global__ __launch_bounds__(256) void wprep1(
    const float* __restrict__ Wg, const float* __restrict__ Zg, u16* __restrict__ out)
{
    __shared__ u16 T[64][72];
    const int tid = threadIdx.x;
    const int kt = blockIdx.x, ct = blockIdx.y, z = blockIdx.z;
    const int k0 = kt * 64;
    const float* wbase = (k0 < 256)
        ? Wg + (size_t)(z * 256 + k0) * 256
        : Zg + (size_t)(z * 256 + (k0 - 256)) * 256;

    const int colg = ct * 64 + (tid & 15) * 4;
    #pragma unroll
    for (int it = 0; it < 4; ++it) {
        const int krl = (tid >> 4) + it * 16;
        const float4 v = *(const float4*)(wbase + (size_t)krl * 256 + colg);
        const int cl = (tid & 15) * 4;
        T[cl + 0][krl] = f2b(v.x); T[cl + 1][krl] = f2b(v.y);
        T[cl + 2][krl] = f2b(v.z); T[cl + 3][krl] = f2b(v.w);
    }
    __syncthreads();
    const int col_l = tid >> 2, ks = (tid & 3) * 16;
    const int ktile = 2 * kt + (ks >> 5);
    const int koff  = ks & 31;
    u16* dst = out + (size_t)z * 131072 + (size_t)ktile * 8192
                   + (size_t)(ct * 64 + col_l) * 32 + koff;
    u16x8 w0, w1;
    #pragma unroll
    for (int j = 0; j < 8; ++j) { w0[j] = T[col_l][ks + j]; w1[j] = T[col_l][ks + 8 + j]; }
    *(u16x8*)(dst) = w0; *(u16x8*)(dst + 8) = w1;
}

// ===========================================================================
// A-prepass: gathered A (7 segments, zero-padded) -> bf16 [n][kt][784][32].
// ===========================================================================
__global__ __launch_bounds__(256) void aprep(
    const float* __restrict__ p,   const float* __restrict__ h,
    const float* __restrict__ g_t, const float* __restrict__ g_s,
    u16* __restrict__ Abf)
{
    const int tid = threadIdx.x;
    const int bx = blockIdx.x, kt = blockIdx.y, n = blockIdx.z;
    const int row = bx * 64 + (tid >> 2);
    if (row >= MR) return;
    const int c  = tid & 3;
    const int kg = kt * 32 + c * 8;
    const int seg = kg >> 8, koff = kg & 255;
    const int ec = (row * NN + n) * 256 + koff;
    const float* src = nullptr; bool valid = true;
    switch (seg) {
        case 0: src = p + ec; break;
        case 1: valid = (n > 0);          src = h + ec - 256; break;
        case 2: src = h + ec; break;
        case 3: valid = (n < NN - 1);     src = h + ec + 256; break;
        case 4: valid = (row % TT) != 0;  src = h + ec - NN * 256; break;
        case 5: src = g_t + ec; break;
        default: src = g_s + ec; break;
    }
    float4 lo = {0.f,0.f,0.f,0.f}, hi = lo;
    if (valid) { lo = *(const float4*)src; hi = *(const float4*)(src + 4); }
    u16x8 w;
    w[0] = f2b(lo.x); w[1] = f2b(lo.y); w[2] = f2b(lo.z); w[3] = f2b(lo.w);
    w[4] = f2b(hi.x); w[5] = f2b(hi.y); w[6] = f2b(hi.z); w[7] = f2b(hi.w);
    *(u16x8*)(Abf + ((size_t)(n * 56 + kt) * MR + row) * 32 + c * 8) = w;
}

// ===========================================================================
// Phase 0 fast path: pure-DMA K-loop. A and B both global->LDS via
// global_load_lds (linear dest, pre-swizzled per-lane source; read XOR as r8).
// Per kt: 10 DMA + 13 ds_read + 36 MFMA. Only barrier drains vmcnt.
// ===========================================================================
#define AB2 2048                 // elems per A buf
#define BB2 18432                // elems per B buf (9*2048)

__global__ __launch_bounds__(256, 2) void fused_cell5(
    const float* __restrict__ c_h, const float* __restrict__ c_g_t,
    const float* __restrict__ c_g_s,
    const u16* __restrict__ Abf, const u16* __restrict__ WT0,
    const float* __restrict__ Bias,
    float* __restrict__ h_new, float* __restrict__ c_h_new)
{
    extern __shared__ u16 smem[];   // [A0|A1|B0|B1] = 40960 elems

    const int tid = threadIdx.x;
    const int lin = blockIdx.x;
    const int xcd = lin & 7, j = lin >> 3;
    const int mtile = j % 13;
    const int slab  = (j / 13) * 8 + xcd;   // 0..95
    const int ntile = slab & 3, n = slab >> 2;

    const int s_r = tid >> 2, s_c = tid & 3;
    const int wro = s_r * 32 + ((s_c ^ ((s_r >> 1) & 3)) << 3);

    const int wave = tid >> 6, lane = tid & 63;
    const int lrow = lane & 15, lci = lane >> 4;

    int aro[4];
    #pragma unroll
    for (int m = 0; m < 4; ++m) {
        const int row = m * 16 + lrow;
        aro[m] = row * 32 + ((lci ^ ((row >> 1) & 3)) << 3);
    }
    const int colr = wave * 16 + lrow;
    const int bro  = colr * 32 + ((lci ^ ((colr >> 1) & 3)) << 3);

    // pre-swizzled per-lane DMA sources (linear LDS dest = tid*16B)
    const u16* abase = Abf + ((size_t)(n * 56) * MR + mtile * 64) * 32 + wro;
    const u16* wbase = WT0 + (size_t)n * 458752 + (size_t)(ntile * 64) * 32 + wro;

    f32x4 acc[9][4];
    #pragma unroll
    for (int g = 0; g < 9; ++g)
        #pragma unroll
        for (int m = 0; m < 4; ++m) acc[g][m] = f32x4{0.f, 0.f, 0.f, 0.f};

    auto dma = [&](int kt, int buf) {
        gld16(abase + (size_t)kt * (MR * 32), &smem[buf * AB2 + tid * 8]);
        const u16* wb = wbase + (size_t)kt * 8192;
        u16* dst = &smem[2 * AB2 + buf * BB2 + tid * 8];
        #pragma unroll
        for (int g = 0; g < 9; ++g)
            gld16(wb + (size_t)g * 11010048, dst + g * 2048);
    };
    auto domfma = [&](int buf) {
        const u16* Asb = smem + buf * AB2;
        const u16* Bsb = smem + 2 * AB2 + buf * BB2;
        s16x8 af[4];
        #pragma unroll
        for (int m = 0; m < 4; ++m) af[m] = *(const s16x8*)(&Asb[aro[m]]);
        __builtin_amdgcn_s_setprio(1);
        #pragma unroll
        for (int g = 0; g < 9; ++g) {
            const s16x8 bf = *(const s16x8*)(&Bsb[g * 2048 + bro]);
            #pragma unroll
            for (int m = 0; m < 4; ++m)
                acc[g][m] = __builtin_amdgcn_mfma_f32_16x16x32_bf16(af[m], bf, acc[g][m], 0, 0, 0);
        }
        __builtin_amdgcn_s_setprio(0);
    };

    dma(0, 0);
    for (int kt = 0; kt < 56; kt += 2) {
        __syncthreads();                 // drains DMA(kt) -> buf0 ready
        dma(kt + 1, 1);                  // prefetch under MFMA
        domfma(0);
        __syncthreads();                 // drains DMA(kt+1) -> buf1 ready
        if (kt + 2 < 56) dma(kt + 2, 0);
        domfma(1);
    }

    // ---- epilogue: bias + cell update, f32 stores
    const int col = ntile * 64 + wave * 16 + lrow;
    float bv[9];
    #pragma unroll
    for (int g = 0; g < 9; ++g) bv[g] = Bias[(g * NN + n) * 256 + col];

    #pragma unroll
    for (int m = 0; m < 4; ++m) {
        #pragma unroll
        for (int i = 0; i < 4; ++i) {
            const int row = mtile * 64 + m * 16 + (lane >> 4) * 4 + i;
            if (row < MR) {
                const size_t e = ((size_t)(row * NN + n)) * 256 + col;
                const float i_n  = sig_(acc[0][m][i] + bv[0]);
                const float f_lt = sig_(acc[1][m][i] + bv[1]);
                const float f_ft = sig_(acc[2][m][i] + bv[2]);
                const float f_rt = sig_(acc[3][m][i] + bv[3]);
                const float f_s  = sig_(acc[4][m][i] + bv[4]);
                const float f_gt = sig_(acc[5][m][i] + bv[5]);
                const float f_gs = sig_(acc[6][m][i] + bv[6]);
                const float o_n  = sig_(acc[7][m][i] + bv[7]);
                const float c_n  = tanh_(acc[8][m][i] + bv[8]);
                const float cb = (n > 0)      ? c_h[e - 256] : 0.f;
                const float ca = (n < NN - 1) ? c_h[e + 256] : 0.f;
                const float cs = (row % TT)   ? c_h[e - NN * 256] : 0.f;
                const float cn = f_lt * cb + f_ft * c_h[e] + f_rt * ca
                               + f_s * cs + f_gt * c_g_t[e] + f_gs * c_g_s[e]
                               + i_n * c_n;
                c_h_new[e] = cn;
                h_new[e]   = o_n * tanh_(cn);
            }
        }
    }
}

// ===========================================================================
// Phase 0 fallback (r8 kernel, unchanged): used when ws too small for Abf.
// ===========================================================================
__global__ __launch_bounds__(256, 2) void fused_cell4(
    const float* __restrict__ p,   const float* __restrict__ h,
    const float* __restrict__ c_h, const float* __restrict__ g_t,
    const float* __restrict__ c_g_t, const float* __restrict__ g_s,
    const float* __restrict__ c_g_s,
    const u16* __restrict__ WT0, const float* __restrict__ Bias,
    float* __restrict__ h_new, float* __restrict__ c_h_new)
{
    extern __shared__ u16 smem[];

    const int tid = threadIdx.x;
    const int lin = blockIdx.x;
    const int xcd = lin & 7, j = lin >> 3;
    const int mtile = j % 13;
    const int slab  = (j / 13) * 8 + xcd;
    const int ntile = slab & 3, n = slab >> 2;

    const int s_r = tid >> 2, s_c = tid & 3;
    const int gr  = mtile * 64 + s_r;
    const bool mval = (gr < MR);
    const int ec = (gr * NN + n) * 256;
    const bool vnb = (n > 0), vna = (n < NN - 1), vtp = (gr % TT) != 0;

    const int wro = s_r * 32 + ((s_c ^ ((s_r >> 1) & 3)) << 3);

    const int wave = tid >> 6, lane = tid & 63;
    const int lrow = lane & 15, lci = lane >> 4;

    int aro[4];
    #pragma unroll
    for (int m = 0; m < 4; ++m) {
        const int row = m * 16 + lrow;
        aro[m] = row * 32 + ((lci ^ ((row >> 1) & 3)) << 3);
    }
    const int colr = wave * 16 + lrow;
    const int bro  = colr * 32 + ((lci ^ ((colr >> 1) & 3)) << 3);

    const size_t bsrc = (size_t)(ntile * 64) * 32 + (size_t)wro;
    const u16* wbase = WT0 + (size_t)n * 458752 + bsrc;

    f32x4 acc[9][4];
    #pragma unroll
    for (int g = 0; g < 9; ++g)
        #pragma unroll
        for (int m = 0; m < 4; ++m) acc[g][m] = f32x4{0.f, 0.f, 0.f, 0.f};

    float4 alo, ahi;

    auto loadA = [&](int kt) {
        const int K0 = kt * 32, seg = K0 >> 8, koff = (K0 & 255) + s_c * 8;
        const float* src = nullptr; bool valid = mval;
        switch (seg) {
            case 0: src = p + ec + koff; break;
            case 1: valid &= vnb; src = h + ec - 256 + koff; break;
            case 2: src = h + ec + koff; break;
            case 3: valid &= vna; src = h + ec + 256 + koff; break;
            case 4: valid &= vtp; src = h + ec - NN * 256 + koff; break;
            case 5: src = g_t + ec + koff; break;
            default: src = g_s + ec + koff; break;
        }
        alo = make_float4(0.f, 0.f, 0.f, 0.f); ahi = alo;
        if (valid) { alo = *(const float4*)src; ahi = *(const float4*)(src + 4); }
    };
    auto storeA = [&](int buf) {
        u16x8 aw;
        aw[0] = f2b(alo.x); aw[1] = f2b(alo.y); aw[2] = f2b(alo.z); aw[3] = f2b(alo.w);
        aw[4] = f2b(ahi.x); aw[5] = f2b(ahi.y); aw[6] = f2b(ahi.z); aw[7] = f2b(ahi.w);
        *(u16x8*)(&smem[buf * AB2 + wro]) = aw;
    };
    auto dmaB = [&](int kt, int buf) {
        const u16* wb = wbase + (size_t)kt * 8192;
        u16* dst = &smem[2 * AB2 + buf * BB2 + tid * 8];
        #pragma unroll
        for (int g = 0; g < 9; ++g)
            gld16(wb + (size_t)g * 11010048, dst + g * 2048);
    };
    auto domfma = [&](int buf) {
        const u16* Asb = smem + buf * AB2;
        const u16* Bsb = smem + 2 * AB2 + buf * BB2;
        s16x8 af[4];
        #pragma unroll
        for (int m = 0; m < 4; ++m) af[m] = *(const s16x8*)(&Asb[aro[m]]);
        __builtin_amdgcn_s_setprio(1);
        #pragma unroll
        for (int g = 0; g < 9; ++g) {
            const s16x8 bf = *(const s16x8*)(&Bsb[g * 2048 + bro]);
            #pragma unroll
            for (int m = 0; m < 4; ++m)
                acc[g][m] = __builtin_amdgcn_mfma_f32_16x16x32_bf16(af[m], bf, acc[g][m], 0, 0, 0);
        }
        __builtin_amdgcn_s_setprio(0);
    };

    dmaB(0, 0); loadA(0); storeA(0);
    for (int kt = 0; kt < 56; kt += 2) {
        __syncthreads();
        loadA(kt + 1); dmaB(kt + 1, 1);
        domfma(0);
        storeA(1);
        __syncthreads();
        if (kt + 2 < 56) { loadA(kt + 2); dmaB(kt + 2, 0); }
        domfma(1);
        if (kt + 2 < 56) storeA(0);
    }

    const int col = ntile * 64 + wave * 16 + lrow;
    float bv[9];
    #pragma unroll
    for (int g = 0; g < 9; ++g) bv[g] = Bias[(g * NN + n) * 256 + col];

    #pragma unroll
    for (int m = 0; m < 4; ++m) {
        #pragma unroll
        for (int i = 0; i < 4; ++i) {
            const int row = mtile * 64 + m * 16 + (lane >> 4) * 4 + i;
            if (row < MR) {
                const size_t e = ((size_t)(row * NN + n)) * 256 + col;
                const float i_n  = sig_(acc[0][m][i] + bv[0]);
                const float f_lt = sig_(acc[1][m][i] + bv[1]);
                const float f_ft = sig_(acc[2][m][i] + bv[2]);
                const float f_rt = sig_(acc[3][m][i] + bv[3]);
                const float f_s  = sig_(acc[4][m][i] + bv[4]);
                const float f_gt = sig_(acc[5][m][i] + bv[5]);
                const float f_gs = sig_(acc[6][m][i] + bv[6]);
                const float o_n  = sig_(acc[7][m][i] + bv[7]);
                const float c_n  = tanh_(acc[8][m][i] + bv[8]);
                const float cb = (n > 0)      ? c_h[e - 256] : 0.f;
                const float ca = (n < NN - 1) ? c_h[e + 256] : 0.f;
                const float cs = (row % TT)   ? c_h[e - NN * 256] : 0.f;
                const float cn = f_lt * cb + f_ft * c_h[e] + f_rt * ca
                               + f_s * cs + f_gt * c_g_t[e] + f_gs * c_g_s[e]
                               + i_n * c_n;
                c_h_new[e] = cn;
                h_new[e]   = o_n * tanh_(cn);
            }
        }
    }
}

// ===========================================================================
// Phase 1: 64x64 tile, 3 gates, K=512. DMA-B; loadA issued BEFORE dmaB so
// storeA's vmcnt wait no longer drains the prefetch DMA.
// ===========================================================================
__global__ __launch_bounds__(256, 4) void fused_global4(
    const float* __restrict__ hn,   const float* __restrict__ g_t,
    const float* __restrict__ g_s,  const float* __restrict__ c_g_t,
    const float* __restrict__ c_g_s,
    const u16* __restrict__ WT1, const float* __restrict__ Bg,
    float* __restrict__ out2, float* __restrict__ out3,
    float* __restrict__ out4, float* __restrict__ out5)
{
    __shared__ u16 smem[2 * 2048 + 2 * 6144];

    const int tid = threadIdx.x;
    const int lin = blockIdx.x;
    const int xcd = lin & 7, j = lin >> 3;
    const int mtile = j % 13;
    const int slab  = (j / 13) * 8 + xcd;   // 0..191
    const int ntile = slab & 3;
    const int zz    = slab >> 2;            // 0..47
    const int n = zz % NN, grp = zz / NN;

    const float* xg = grp ? g_s : g_t;
    const float* cg = grp ? c_g_s : c_g_t;
    float* og  = grp ? out4 : out2;
    float* ocg = grp ? out5 : out3;

    const int s_r = tid >> 2, s_c = tid & 3;
    const int gr  = mtile * 64 + s_r;
    const bool mval = (gr < MR);
    const int ec = (gr * NN + n) * 256;

    const int wro = s_r * 32 + ((s_c ^ ((s_r >> 1) & 3)) << 3);

    const int wave = tid >> 6, lane = tid & 63;
    const int lrow = lane & 15, lci = lane >> 4;

    int aro[4];
    #pragma unroll
    for (int m = 0; m < 4; ++m) {
        const int row = m * 16 + lrow;
        aro[m] = row * 32 + ((lci ^ ((row >> 1) & 3)) << 3);
    }
    const int colr = wave * 16 + lrow;
    const int bro  = colr * 32 + ((lci ^ ((colr >> 1) & 3)) << 3);

    const size_t bsrc = (size_t)(ntile * 64) * 32 + (size_t)wro;
    const u16* wbase = WT1 + (size_t)(grp * 3 * NN + n) * 131072 + bsrc;

    f32x4 acc[3][4];
    #pragma unroll
    for (int g = 0; g < 3; ++g)
        #pragma unroll
        for (int m = 0; m < 4; ++m) acc[g][m] = f32x4{0.f, 0.f, 0.f, 0.f};

    float4 alo, ahi;

    auto loadA = [&](int kt) {
        const int K0 = kt * 32, koff = (K0 & 255) + s_c * 8;
        const float* src = ((K0 < 256) ? hn : xg) + ec + koff;
        alo = make_float4(0.f, 0.f, 0.f, 0.f); ahi = alo;
        if (mval) { alo = *(const float4*)src; ahi = *(const float4*)(src + 4); }
    };
    auto storeA = [&](int buf) {
        u16x8 aw;
        aw[0] = f2b(alo.x); aw[1] = f2b(alo.y); aw[2] = f2b(alo.z); aw[3] = f2b(alo.w);
        aw[4] = f2b(ahi.x); aw[5] = f2b(ahi.y); aw[6] = f2b(ahi.z); aw[7] = f2b(ahi.w);
        *(u16x8*)(&smem[buf * 2048 + wro]) = aw;
    };
    auto dmaB = [&](int kt, int buf) {
        const u16* wb = wbase + (size_t)kt * 8192;
        u16* dst = &smem[2 * 2048 + buf * 6144 + tid * 8];
        #pragma unroll
        for (int g = 0; g < 3; ++g)
            gld16(wb + (size_t)g * 3145728, dst + g * 2048);
    };
    auto domfma = [&](int buf) {
        const u16* Asb = smem + buf * 2048;
        const u16* Bsb = smem + 2 * 2048 + buf * 6144;
        s16x8 af[4];
        #pragma unroll
        for (int m = 0; m < 4; ++m) af[m] = *(const s16x8*)(&Asb[aro[m]]);
        __builtin_amdgcn_s_setprio(1);
        #pragma unroll
        for (int g = 0; g < 3; ++g) {
            const s16x8 bf = *(const s16x8*)(&Bsb[g * 2048 + bro]);
            #pragma unroll
            for (int m = 0; m < 4; ++m)
                acc[g][m] = __builtin_amdgcn_mfma_f32_16x16x32_bf16(af[m], bf, acc[g][m], 0, 0, 0);
        }
        __builtin_amdgcn_s_setprio(0);
    };

    loadA(0); dmaB(0, 0); storeA(0);
    for (int kt = 0; kt < 16; kt += 2) {
        __syncthreads();
        loadA(kt + 1); dmaB(kt + 1, 1);
        domfma(0);
        storeA(1);
        __syncthreads();
        if (kt + 2 < 16) { loadA(kt + 2); dmaB(kt + 2, 0); }
        domfma(1);
        if (kt + 2 < 16) storeA(0);
    }

    const int col = ntile * 64 + wave * 16 + lrow;
    float bv[3];
    #pragma unroll
    for (int g = 0; g < 3; ++g) bv[g] = Bg[((grp * 3 + g) * NN + n) * 256 + col];

    #pragma unroll
    for (int m = 0; m < 4; ++m) {
        #pragma unroll
        for (int i = 0; i < 4; ++i) {
            const int row = mtile * 64 + m * 16 + (lane >> 4) * 4 + i;
            if (row < MR) {
                const size_t e = ((size_t)(row * NN + n)) * 256 + col;
                const float f    = sig_(acc[0][m][i] + bv[0]);
                const float cand = tanh_(acc[1][m][i] + bv[1]);
                const float o    = sig_(acc[2][m][i] + bv[2]);
                const float cn = f * cg[e] + (1.f - f) * cand;
                ocg[e] = cn;
                og[e]  = o * tanh_(cn);
            }
        }
    }
}

extern "C" void kernel_launch(void* const* d_in, const int* in_sizes, int n_in,
                              void* d_out, int out_size, void* d_ws, size_t ws_size,
                              hipStream_t stream)
{
    const float* h     = (const float*)d_in[0];
    const float* c_h   = (const float*)d_in[1];
    const float* p     = (const float*)d_in[2];
    const float* g_t   = (const float*)d_in[3];
    const float* c_g_t = (const float*)d_in[4];
    const float* g_s   = (const float*)d_in[5];
    const float* c_g_s = (const float*)d_in[6];
    const float* U     = (const float*)d_in[7];
    const float* Wt    = (const float*)d_in[8];
    const float* Ws    = (const float*)d_in[9];
    const float* Zt    = (const float*)d_in[10];
    const float* Zs    = (const float*)d_in[11];
    const float* bb    = (const float*)d_in[12];
    const float* Wg    = (const float*)d_in[13];
    const float* Zg    = (const float*)d_in[14];
    const float* bg    = (const float*)d_in[15];

    float* out0 = (float*)d_out;        // h_new
    float* out1 = out0 + (size_t)SZT;   // c_h_new
    float* out2 = out1 + (size_t)SZT;   // g_t_new
    float* out3 = out2 + (size_t)SZT;   // c_g_t_new
    float* out4 = out3 + (size_t)SZT;   // g_s_new
    float* out5 = out4 + (size_t)SZT;   // c_g_s_new

    u16* wt0 = (u16*)d_ws;
    u16* wt1 = wt0 + WT0_ELEMS;
    u16* abf = wt1 + WT1_ELEMS;

    dim3 blk(256);
    wprep0<<<dim3(28, 4, 216), blk, 0, stream>>>(U, Wt, Ws, Zt, Zs, wt0);
    wprep1<<<dim3(8, 4, 144), blk, 0, stream>>>(Wg, Zg, wt1);

    if (ws_size >= NEED_A) {
        aprep<<<dim3(13, 56, 24), blk, 0, stream>>>(p, h, g_t, g_s, abf);
        hipFuncSetAttribute((const void*)fused_cell5,
                            hipFuncAttributeMaxDynamicSharedMemorySize, 81920);
        fused_cell5<<<dim3(1248), blk, 81920, stream>>>(
            c_h, c_g_t, c_g_s, abf, wt0, bb, out0, out1);
    } else {
        hipFuncSetAttribute((const void*)fused_cell4,
                            hipFuncAttributeMaxDynamicSharedMemorySize, 81920);
        fused_cell4<<<dim3(1248), blk, 81920, stream>>>(
            p, h, c_h, g_t, c_g_t, g_s, c_g_s, wt0, bb, out0, out1);
    }
    fused_global4<<<dim3(2496), blk, 0, stream>>>(
        out0, g_t, g_s, c_g_t, c_g_s, wt1, bg, out2, out3, out4, out5);
}

// Round 10
// 467.817 us; speedup vs baseline: 1.0952x; 1.0952x over previous
//
#include <hip/hip_runtime.h>
#include <hip/hip_bf16.h>

typedef unsigned short u16;
typedef u16 u16x8 __attribute__((ext_vector_type(8)));
typedef short s16x8 __attribute__((ext_vector_type(8)));
typedef float f32x4 __attribute__((ext_vector_type(4)));
typedef unsigned int u32;

#define NN 24
#define TT 49
#define MR 784                  // B*T = 16*49
#define SZT 4816896             // B*T*N*H

__device__ inline u16 f2b(float f){
    __hip_bfloat16 b = __float2bfloat16(f); u16 r; __builtin_memcpy(&r, &b, 2); return r;
}
__device__ inline float sig_(float x){ return 1.f / (1.f + __expf(-x)); }
__device__ inline float tanh_(float x){ float e = __expf(2.f * x); return (e - 1.f) / (e + 1.f); }

__device__ inline void gld16(const u16* g, u16* l){
    __builtin_amdgcn_global_load_lds(
        (const __attribute__((address_space(1))) unsigned int*)g,
        (__attribute__((address_space(3))) unsigned int*)l, 16, 0, 0);
}

#define BAR()      __builtin_amdgcn_s_barrier()
#define WAITVM(N)  asm volatile("s_waitcnt vmcnt(" #N ")" ::: "memory")
#define WAITVL(N)  asm volatile("s_waitcnt vmcnt(" #N ") lgkmcnt(0)" ::: "memory")

// ws layout: WT0 bf16 [216][56][256][32] | WT1 bf16 [144][16][256][32] | Abf bf16 [24][56][784][32]
#define WT0_ELEMS ((size_t)216 * 256 * 1792)
#define WT1_ELEMS ((size_t)144 * 256 * 512)

// ===========================================================================
// Merged prepass: wprep0 (24192 blk) | wprep1 (4608 blk) | aprep (17472 blk)
// ===========================================================================
__global__ __launch_bounds__(256) void prep_all(
    const float* __restrict__ U,  const float* __restrict__ Wt,
    const float* __restrict__ Ws, const float* __restrict__ Zt,
    const float* __restrict__ Zs, const float* __restrict__ Wg,
    const float* __restrict__ Zg,
    const float* __restrict__ p,  const float* __restrict__ h,
    const float* __restrict__ g_t, const float* __restrict__ g_s,
    u16* __restrict__ wt0, u16* __restrict__ wt1, u16* __restrict__ Abf)
{
    __shared__ u16 T[64][72];
    const int tid = threadIdx.x;
    const int lin = blockIdx.x;

    if (lin < 24192) {
        // ---- wprep0: weights f32 [k][col] -> bf16 [kt][col][32]
        const int kt = lin % 28, ct = (lin / 28) % 4, z = lin / 112;
        const int n = z % NN, g = z / NN;
        const int k0 = kt * 64;
        const float* wbase;
        if (k0 < 256)       wbase = U  + (size_t)((g * NN + n) * 256 + k0)          * 256;
        else if (k0 < 1024) wbase = Wt + (size_t)((g * NN + n) * 768 + (k0 - 256))  * 256;
        else if (k0 < 1280) wbase = Ws + (size_t)((g * NN + n) * 256 + (k0 - 1024)) * 256;
        else if (k0 < 1536) wbase = Zt + (size_t)((g * NN + n) * 256 + (k0 - 1280)) * 256;
        else { const int g2 = (g == 2) ? 1 : g;      // Zs_eff: f_ft uses Zs[lt]
               wbase = Zs + (size_t)((g2 * NN + n) * 256 + (k0 - 1536)) * 256; }
        const int colg = ct * 64 + (tid & 15) * 4;
        #pragma unroll
        for (int it = 0; it < 4; ++it) {
            const int krl = (tid >> 4) + it * 16;
            const float4 v = *(const float4*)(wbase + (size_t)krl * 256 + colg);
            const int cl = (tid & 15) * 4;
            T[cl + 0][krl] = f2b(v.x); T[cl + 1][krl] = f2b(v.y);
            T[cl + 2][krl] = f2b(v.z); T[cl + 3][krl] = f2b(v.w);
        }
        __syncthreads();
        const int col_l = tid >> 2, ks = (tid & 3) * 16;
        const int ktile = 2 * kt + (ks >> 5);
        const int koff  = ks & 31;
        u16* dst = wt0 + (size_t)z * 458752 + (size_t)ktile * 8192
                       + (size_t)(ct * 64 + col_l) * 32 + koff;
        u16x8 w0, w1;
        #pragma unroll
        for (int j2 = 0; j2 < 8; ++j2) { w0[j2] = T[col_l][ks + j2]; w1[j2] = T[col_l][ks + 8 + j2]; }
        *(u16x8*)(dst) = w0; *(u16x8*)(dst + 8) = w1;
    } else if (lin < 28800) {
        // ---- wprep1
        const int l = lin - 24192;
        const int kt = l % 8, ct = (l / 8) % 4, z = l / 32;
        const int k0 = kt * 64;
        const float* wbase = (k0 < 256)
            ? Wg + (size_t)(z * 256 + k0) * 256
            : Zg + (size_t)(z * 256 + (k0 - 256)) * 256;
        const int colg = ct * 64 + (tid & 15) * 4;
        #pragma unroll
        for (int it = 0; it < 4; ++it) {
            const int krl = (tid >> 4) + it * 16;
            const float4 v = *(const float4*)(wbase + (size_t)krl * 256 + colg);
            const int cl = (tid & 15) * 4;
            T[cl + 0][krl] = f2b(v.x); T[cl + 1][krl] = f2b(v.y);
            T[cl + 2][krl] = f2b(v.z); T[cl + 3][krl] = f2b(v.w);
        }
        __syncthreads();
        const int col_l = tid >> 2, ks = (tid & 3) * 16;
        const int ktile = 2 * kt + (ks >> 5);
        const int koff  = ks & 31;
        u16* dst = wt1 + (size_t)z * 131072 + (size_t)ktile * 8192
                       + (size_t)(ct * 64 + col_l) * 32 + koff;
        u16x8 w0, w1;
        #pragma unroll
        for (int j2 = 0; j2 < 8; ++j2) { w0[j2] = T[col_l][ks + j2]; w1[j2] = T[col_l][ks + 8 + j2]; }
        *(u16x8*)(dst) = w0; *(u16x8*)(dst + 8) = w1;
    } else {
        // ---- aprep: gathered A (7 segments, zero-padded) -> bf16 [n][kt][784][32]
        const int l = lin - 28800;
        const int bx = l % 13, kt = (l / 13) % 56, n = l / 728;
        const int row = bx * 64 + (tid >> 2);
        if (row >= MR) return;
        const int c  = tid & 3;
        const int kg = kt * 32 + c * 8;
        const int seg = kg >> 8, koff = kg & 255;
        const int ec = (row * NN + n) * 256 + koff;
        const float* src = nullptr; bool valid = true;
        switch (seg) {
            case 0: src = p + ec; break;
            case 1: valid = (n > 0);          src = h + ec - 256; break;
            case 2: src = h + ec; break;
            case 3: valid = (n < NN - 1);     src = h + ec + 256; break;
            case 4: valid = (row % TT) != 0;  src = h + ec - NN * 256; break;
            case 5: src = g_t + ec; break;
            default: src = g_s + ec; break;
        }
        float4 lo = {0.f,0.f,0.f,0.f}, hi = lo;
        if (valid) { lo = *(const float4*)src; hi = *(const float4*)(src + 4); }
        u16x8 w;
        w[0] = f2b(lo.x); w[1] = f2b(lo.y); w[2] = f2b(lo.z); w[3] = f2b(lo.w);
        w[4] = f2b(hi.x); w[5] = f2b(hi.y); w[6] = f2b(hi.z); w[7] = f2b(hi.w);
        *(u16x8*)(Abf + ((size_t)(n * 56 + kt) * MR + row) * 32 + c * 8) = w;
    }
}

// ===========================================================================
// Phase 0: pure-DMA K-loop with COUNTED vmcnt publish barriers (T4).
// Per kt: 10 gld16 + read-done s_barrier + vmcnt(10)+s_barrier + 13 ds_read + 36 MFMA.
// ===========================================================================
#define AB2 2048
#define BB2 18432

__global__ __launch_bounds__(256, 2) void fused_cell6(
    const float* __restrict__ c_h, const float* __restrict__ c_g_t,
    const float* __restrict__ c_g_s,
    const u16* __restrict__ Abf, const u16* __restrict__ WT0,
    const float* __restrict__ Bias,
    float* __restrict__ h_new, float* __restrict__ c_h_new)
{
    extern __shared__ u16 smem[];   // [A0|A1|B0|B1]

    const int tid = threadIdx.x;
    const int lin = blockIdx.x;
    const int xcd = lin & 7, j = lin >> 3;
    const int mtile = j % 13;
    const int slab  = (j / 13) * 8 + xcd;   // 0..95
    const int ntile = slab & 3, n = slab >> 2;

    const int s_r = tid >> 2, s_c = tid & 3;
    const int wro = s_r * 32 + ((s_c ^ ((s_r >> 1) & 3)) << 3);

    const int wave = tid >> 6, lane = tid & 63;
    const int lrow = lane & 15, lci = lane >> 4;

    int aro[4];
    #pragma unroll
    for (int m = 0; m < 4; ++m) {
        const int row = m * 16 + lrow;
        aro[m] = row * 32 + ((lci ^ ((row >> 1) & 3)) << 3);
    }
    const int colr = wave * 16 + lrow;
    const int bro  = colr * 32 + ((lci ^ ((colr >> 1) & 3)) << 3);

    const u16* abase = Abf + ((size_t)(n * 56) * MR + mtile * 64) * 32 + wro;
    const u16* wbase = WT0 + (size_t)n * 458752 + (size_t)(ntile * 64) * 32 + wro;

    f32x4 acc[9][4];
    #pragma unroll
    for (int g = 0; g < 9; ++g)
        #pragma unroll
        for (int m = 0; m < 4; ++m) acc[g][m] = f32x4{0.f, 0.f, 0.f, 0.f};

    auto dma = [&](int kt, int buf) {
        gld16(abase + (size_t)kt * (MR * 32), &smem[buf * AB2 + tid * 8]);
        const u16* wb = wbase + (size_t)kt * 8192;
        u16* dst = &smem[2 * AB2 + buf * BB2 + tid * 8];
        #pragma unroll
        for (int g = 0; g < 9; ++g)
            gld16(wb + (size_t)g * 11010048, dst + g * 2048);
    };
    auto domfma = [&](int buf) {
        const u16* Asb = smem + buf * AB2;
        const u16* Bsb = smem + 2 * AB2 + buf * BB2;
        s16x8 af[4];
        #pragma unroll
        for (int m = 0; m < 4; ++m) af[m] = *(const s16x8*)(&Asb[aro[m]]);
        __builtin_amdgcn_s_setprio(1);
        #pragma unroll
        for (int g = 0; g < 9; ++g) {
            const s16x8 bf = *(const s16x8*)(&Bsb[g * 2048 + bro]);
            #pragma unroll
            for (int m = 0; m < 4; ++m)
                acc[g][m] = __builtin_amdgcn_mfma_f32_16x16x32_bf16(af[m], bf, acc[g][m], 0, 0, 0);
        }
        __builtin_amdgcn_s_setprio(0);
    };

    // prologue: publish buf0(kt0), leave buf1(kt1) in flight
    dma(0, 0);
    WAITVM(0); BAR();
    dma(1, 1);                               // 10 in flight
    for (int kt = 0; kt < 54; kt += 2) {
        domfma(0);                           // consume buf0 (kt)
        BAR();                               // readers done with buf0
        dma(kt + 2, 0);                      // 20 in flight
        WAITVM(10); BAR();                   // publish buf1 (kt+1); kt+2 stays in flight
        domfma(1);                           // consume buf1 (kt+1)
        BAR();                               // readers done with buf1
        dma(kt + 3, 1);                      // 20 in flight
        WAITVM(10); BAR();                   // publish buf0 (kt+2)
    }
    domfma(0);                               // kt = 54
    BAR();
    WAITVM(0); BAR();                        // publish buf1 (55)
    domfma(1);                               // kt = 55

    // ---- epilogue: bias + cell update, f32 stores
    const int col = ntile * 64 + wave * 16 + lrow;
    float bv[9];
    #pragma unroll
    for (int g = 0; g < 9; ++g) bv[g] = Bias[(g * NN + n) * 256 + col];

    #pragma unroll
    for (int m = 0; m < 4; ++m) {
        #pragma unroll
        for (int i = 0; i < 4; ++i) {
            const int row = mtile * 64 + m * 16 + (lane >> 4) * 4 + i;
            if (row < MR) {
                const size_t e = ((size_t)(row * NN + n)) * 256 + col;
                const float i_n  = sig_(acc[0][m][i] + bv[0]);
                const float f_lt = sig_(acc[1][m][i] + bv[1]);
                const float f_ft = sig_(acc[2][m][i] + bv[2]);
                const float f_rt = sig_(acc[3][m][i] + bv[3]);
                const float f_s  = sig_(acc[4][m][i] + bv[4]);
                const float f_gt = sig_(acc[5][m][i] + bv[5]);
                const float f_gs = sig_(acc[6][m][i] + bv[6]);
                const float o_n  = sig_(acc[7][m][i] + bv[7]);
                const float c_n  = tanh_(acc[8][m][i] + bv[8]);
                const float cb = (n > 0)      ? c_h[e - 256] : 0.f;
                const float ca = (n < NN - 1) ? c_h[e + 256] : 0.f;
                const float cs = (row % TT)   ? c_h[e - NN * 256] : 0.f;
                const float cn = f_lt * cb + f_ft * c_h[e] + f_rt * ca
                               + f_s * cs + f_gt * c_g_t[e] + f_gs * c_g_s[e]
                               + i_n * c_n;
                c_h_new[e] = cn;
                h_new[e]   = o_n * tanh_(cn);
            }
        }
    }
}

// ===========================================================================
// Phase 1: counted-vmcnt pipeline + T14 split A-staging (load early, store late).
// Per kt: 2 f32 A-loads + 3 B-DMA + 1 ds_write + counted publish (vmcnt(5)).
// ===========================================================================
__global__ __launch_bounds__(256, 4) void fused_global5(
    const float* __restrict__ hn,   const float* __restrict__ g_t,
    const float* __restrict__ g_s,  const float* __restrict__ c_g_t,
    const float* __restrict__ c_g_s,
    const u16* __restrict__ WT1, const float* __restrict__ Bg,
    float* __restrict__ out2, float* __restrict__ out3,
    float* __restrict__ out4, float* __restrict__ out5)
{
    __shared__ u16 smem[2 * 2048 + 2 * 6144];

    const int tid = threadIdx.x;
    const int lin = blockIdx.x;
    const int xcd = lin & 7, j = lin >> 3;
    const int mtile = j % 13;
    const int slab  = (j / 13) * 8 + xcd;   // 0..191
    const int ntile = slab & 3;
    const int zz    = slab >> 2;            // 0..47
    const int n = zz % NN, grp = zz / NN;

    const float* xg = grp ? g_s : g_t;
    const float* cg = grp ? c_g_s : c_g_t;
    float* og  = grp ? out4 : out2;
    float* ocg = grp ? out5 : out3;

    const int s_r = tid >> 2, s_c = tid & 3;
    const int gr  = mtile * 64 + s_r;
    const bool mval = (gr < MR);
    const int ec = (gr * NN + n) * 256;

    const int wro = s_r * 32 + ((s_c ^ ((s_r >> 1) & 3)) << 3);

    const int wave = tid >> 6, lane = tid & 63;
    const int lrow = lane & 15, lci = lane >> 4;

    int aro[4];
    #pragma unroll
    for (int m = 0; m < 4; ++m) {
        const int row = m * 16 + lrow;
        aro[m] = row * 32 + ((lci ^ ((row >> 1) & 3)) << 3);
    }
    const int colr = wave * 16 + lrow;
    const int bro  = colr * 32 + ((lci ^ ((colr >> 1) & 3)) << 3);

    const u16* wbase = WT1 + (size_t)(grp * 3 * NN + n) * 131072
                           + (size_t)(ntile * 64) * 32 + wro;

    f32x4 acc[3][4];
    #pragma unroll
    for (int g = 0; g < 3; ++g)
        #pragma unroll
        for (int m = 0; m < 4; ++m) acc[g][m] = f32x4{0.f, 0.f, 0.f, 0.f};

    float4 aOlo, aOhi, aNlo, aNhi;

    auto loadA = [&](int kt, float4& lo, float4& hi) {
        const int K0 = kt * 32, koff = (K0 & 255) + s_c * 8;
        const float* src = ((K0 < 256) ? hn : xg) + ec + koff;
        lo = make_float4(0.f, 0.f, 0.f, 0.f); hi = lo;
        if (mval) { lo = *(const float4*)src; hi = *(const float4*)(src + 4); }
    };
    auto storeA = [&](int buf, const float4& lo, const float4& hi) {
        u16x8 aw;
        aw[0] = f2b(lo.x); aw[1] = f2b(lo.y); aw[2] = f2b(lo.z); aw[3] = f2b(lo.w);
        aw[4] = f2b(hi.x); aw[5] = f2b(hi.y); aw[6] = f2b(hi.z); aw[7] = f2b(hi.w);
        *(u16x8*)(&smem[buf * 2048 + wro]) = aw;
    };
    auto dmaB = [&](int kt, int buf) {
        const u16* wb = wbase + (size_t)kt * 8192;
        u16* dst = &smem[2 * 2048 + buf * 6144 + tid * 8];
        #pragma unroll
        for (int g = 0; g < 3; ++g)
            gld16(wb + (size_t)g * 3145728, dst + g * 2048);
    };
    auto domfma = [&](int buf) {
        const u16* Asb = smem + buf * 2048;
        const u16* Bsb = smem + 2 * 2048 + buf * 6144;
        s16x8 af[4];
        #pragma unroll
        for (int m = 0; m < 4; ++m) af[m] = *(const s16x8*)(&Asb[aro[m]]);
        __builtin_amdgcn_s_setprio(1);
        #pragma unroll
        for (int g = 0; g < 3; ++g) {
            const s16x8 bf = *(const s16x8*)(&Bsb[g * 2048 + bro]);
            #pragma unroll
            for (int m = 0; m < 4; ++m)
                acc[g][m] = __builtin_amdgcn_mfma_f32_16x16x32_bf16(af[m], bf, acc[g][m], 0, 0, 0);
        }
        __builtin_amdgcn_s_setprio(0);
    };

    // prologue: buf0 = kt0 published; a(1) in regs; B(1) in flight
    loadA(0, aOlo, aOhi);
    dmaB(0, 0);
    storeA(0, aOlo, aOhi);
    loadA(1, aOlo, aOhi);
    dmaB(1, 1);
    WAITVL(5); BAR();                       // B(0) done, ds_write drained -> publish buf0
    for (int kt = 0; kt < 14; kt += 2) {
        domfma(0);                          // kt
        BAR();                              // readers done with buf0
        loadA(kt + 2, aNlo, aNhi);
        dmaB(kt + 2, 0);
        storeA(1, aOlo, aOhi);              // a(kt+1) -> buf1 (auto-wait vmcnt(5))
        WAITVL(5); BAR();                   // publish buf1 (kt+1)
        domfma(1);                          // kt+1
        BAR();                              // readers done with buf1
        loadA(kt + 3, aOlo, aOhi);
        dmaB(kt + 3, 1);
        storeA(0, aNlo, aNhi);              // a(kt+2) -> buf0
        WAITVL(5); BAR();                   // publish buf0 (kt+2)
    }
    domfma(0);                              // kt = 14
    BAR();
    storeA(1, aOlo, aOhi);                  // a(15)
    WAITVL(0); BAR();                       // publish buf1 (15)
    domfma(1);                              // kt = 15

    const int col = ntile * 64 + wave * 16 + lrow;
    float bv[3];
    #pragma unroll
    for (int g = 0; g < 3; ++g) bv[g] = Bg[((grp * 3 + g) * NN + n) * 256 + col];

    #pragma unroll
    for (int m = 0; m < 4; ++m) {
        #pragma unroll
        for (int i = 0; i < 4; ++i) {
            const int row = mtile * 64 + m * 16 + (lane >> 4) * 4 + i;
            if (row < MR) {
                const size_t e = ((size_t)(row * NN + n)) * 256 + col;
                const float f    = sig_(acc[0][m][i] + bv[0]);
                const float cand = tanh_(acc[1][m][i] + bv[1]);
                const float o    = sig_(acc[2][m][i] + bv[2]);
                const float cn = f * cg[e] + (1.f - f) * cand;
                ocg[e] = cn;
                og[e]  = o * tanh_(cn);
            }
        }
    }
}

extern "C" void kernel_launch(void* const* d_in, const int* in_sizes, int n_in,
                              void* d_out, int out_size, void* d_ws, size_t ws_size,
                              hipStream_t stream)
{
    const float* h     = (const float*)d_in[0];
    const float* c_h   = (const float*)d_in[1];
    const float* p     = (const float*)d_in[2];
    const float* g_t   = (const float*)d_in[3];
    const float* c_g_t = (const float*)d_in[4];
    const float* g_s   = (const float*)d_in[5];
    const float* c_g_s = (const float*)d_in[6];
    const float* U     = (const float*)d_in[7];
    const float* Wt    = (const float*)d_in[8];
    const float* Ws    = (const float*)d_in[9];
    const float* Zt    = (const float*)d_in[10];
    const float* Zs    = (const float*)d_in[11];
    const float* bb    = (const float*)d_in[12];
    const float* Wg    = (const float*)d_in[13];
    const float* Zg    = (const float*)d_in[14];
    const float* bg    = (const float*)d_in[15];

    float* out0 = (float*)d_out;        // h_new
    float* out1 = out0 + (size_t)SZT;   // c_h_new
    float* out2 = out1 + (size_t)SZT;   // g_t_new
    float* out3 = out2 + (size_t)SZT;   // c_g_t_new
    float* out4 = out3 + (size_t)SZT;   // g_s_new
    float* out5 = out4 + (size_t)SZT;   // c_g_s_new

    u16* wt0 = (u16*)d_ws;
    u16* wt1 = wt0 + WT0_ELEMS;
    u16* abf = wt1 + WT1_ELEMS;

    dim3 blk(256);
    prep_all<<<dim3(46272), blk, 0, stream>>>(U, Wt, Ws, Zt, Zs, Wg, Zg,
                                              p, h, g_t, g_s, wt0, wt1, abf);

    hipFuncSetAttribute((const void*)fused_cell6,
                        hipFuncAttributeMaxDynamicSharedMemorySize, 81920);
    fused_cell6<<<dim3(1248), blk, 81920, stream>>>(
        c_h, c_g_t, c_g_s, abf, wt0, bb, out0, out1);
    fused_global5<<<dim3(2496), blk, 0, stream>>>(
        out0, g_t, g_s, c_g_t, c_g_s, wt1, bg, out2, out3, out4, out5);
}